// Round 22
// baseline (56.351 us; speedup 1.0000x reference)
//
#include <hip/hip_runtime.h>
#include <hip/hip_fp16.h>

#define W 256
#define NA 180
#define SPLIT 8
#define SWORDS 13100          // window budget (worst-case ~12.6K words @ 45 deg)
#define SALLOC 13200          // 52,800 B -> 3 blocks/CU, 24 waves/CU

// Block = (angle a, batch n, column-quarter cq). Owns 64 columns x full r-range.
// Window = bbox of its (clamped) taps in biased coords (half = px+2, row = py+1),
// staged fp16 with odd word stride; un-staged cells are zero guards.

__global__ __launch_bounds__(512) void radon_kernel(
    const float* __restrict__ x, const int* __restrict__ index_p,
    float* __restrict__ out)
{
    __shared__ unsigned sw[SALLOC];

    const int a = blockIdx.x;
    const int n = blockIdx.y;
    const int cq = blockIdx.z;       // 0..3
    const int tid = threadIdx.x;
    const int cl = tid & 63;         // lane = local column
    const int s = tid >> 6;          // r-chunk 0..7 (wave-uniform)

    const int index = *index_p;
    const int seg[6] = {1, 26, 51, 77, 102, 128};
    const int t0 = seg[4 - index];
    const int t1 = seg[4 - index + 1];
    const int r1lo = 128 - t1;
    const int r0lo = 128 - t0, r0hi = 127 + t0;
    const int total = 2 * t1;

    float sa, ca;
    sincosf((float)a * 0.017453292519943295f, &sa, &ca);

    // ---- window bbox from the 4 (xc, rf) corners (block-uniform) ----
    const float xcl = ((2.0f * (float)(cq * 64) + 1.0f) * (1.0f / 256.0f)) - 1.0f;
    const float xch = ((2.0f * (float)(cq * 64 + 63) + 1.0f) * (1.0f / 256.0f)) - 1.0f;
    const float rfl = (float)r1lo - 127.5f;
    const float rfh = rfl + (float)(total - 1);
    const float bxl = fmaf(128.0f * ca, xcl, 129.5f);
    const float bxh = fmaf(128.0f * ca, xch, 129.5f);
    const float byl = fmaf(-128.0f * sa, xcl, 128.5f);
    const float byh = fmaf(-128.0f * sa, xch, 128.5f);

    float ixmin = fminf(fminf(fmaf(sa, rfl, bxl), fmaf(sa, rfh, bxl)),
                        fminf(fmaf(sa, rfl, bxh), fmaf(sa, rfh, bxh)));
    float ixmax = fmaxf(fmaxf(fmaf(sa, rfl, bxl), fmaf(sa, rfh, bxl)),
                        fmaxf(fmaf(sa, rfl, bxh), fmaf(sa, rfh, bxh)));
    float iymin = fminf(fminf(fmaf(ca, rfl, byl), fmaf(ca, rfh, byl)),
                        fminf(fmaf(ca, rfl, byh), fmaf(ca, rfh, byh)));
    float iymax = fmaxf(fmaxf(fmaf(ca, rfl, byl), fmaf(ca, rfh, byl)),
                        fmaxf(fmaf(ca, rfl, byh), fmaf(ca, rfh, byh)));
    ixmin = __builtin_amdgcn_fmed3f(ixmin, 1.0f, 258.0f);
    ixmax = __builtin_amdgcn_fmed3f(ixmax, 1.0f, 258.0f);
    iymin = __builtin_amdgcn_fmed3f(iymin, 0.0f, 257.0f);
    iymax = __builtin_amdgcn_fmed3f(iymax, 0.0f, 257.0f);

    const int gx0 = ((int)ixmin) & ~1;            // even
    const int gx1 = (int)ixmax + 1;               // max half read
    const int gy0 = (int)iymin;
    const int gy1 = (int)iymax + 1;               // max row read
    const int nw = ((gx1 >> 1) - (gx0 >> 1)) + 2; // words/row incl pad word
    const int stride = nw | 1;                    // odd -> bank spread
    int nrows = gy1 - gy0 + 1;
    nrows = min(nrows, SWORDS / stride);          // OOB protection (never hit for index=2)
    const int nwords = nrows * stride;

    // ---- zero-fill window (guards) ----
    for (int i = tid; i < nwords; i += 512) sw[i] = 0u;
    __syncthreads();

    // ---- stage valid sub-rectangle: float2 groups, px always EVEN ----
    // px in [pxlo, pxhi], px even; no cap/overlap -> no parity hazard (R21 bug fix).
    {
        const float* __restrict__ img = x + (size_t)n * W * W;
        const int pylo = max(gy0 - 1, 0);
        const int pyhi = min(gy1 - 1, 255);
        const int pxlo = max(gx0 - 2, 0);         // even (gx0 even)
        const int pxhi = min(gx1 - 2, 255);
        const int nq2 = (pxhi - pxlo + 2) >> 1;   // float2 groups per row (<= ~80)
        const int lbase = pylo + 1 - gy0;
        const int nlr = pyhi - pylo + 1;
        const int shift = (nq2 <= 64) ? 6 : 7;    // block-uniform slot width
        const int smask = (1 << shift) - 1;
        const int ncell = nlr << shift;
        for (int i = tid; i < ncell; i += 512) {
            const int lr = i >> shift, q = i & smask;
            if (q < nq2) {
                const int px = pxlo + 2 * q;      // even, px+1 <= 255 guaranteed
                const int py = pylo + lr;
                const float2 v = *(const float2*)(img + py * W + px);
                const __half2 hp = __floats2half2_rn(v.x, v.y);
                sw[(lbase + lr) * stride + ((px - (gx0 - 2)) >> 1)] = *(const unsigned*)&hp;
            }
        }
    }
    __syncthreads();

    // ---- tap loop (exact ownership; R19 body + window-local addressing) ----
    const int c = cq * 64 + cl;
    const float xc = ((2.0f * (float)c + 1.0f) * (1.0f / 256.0f)) - 1.0f;
    const float bx = fmaf(128.0f * ca, xc, 129.5f);
    const float by = fmaf(-128.0f * sa, xc, 128.5f);
    const int wbase = -(gy0 * stride + (gx0 >> 1));

    const int chunk = (total + SPLIT - 1) / SPLIT;
    const int rs = r1lo + s * chunk;
    const int re = min(rs + chunk, r1lo + total);

#define TAP_BODY                                                              \
        float ix = fmaf(sa, rf, bx);                                          \
        float iy = fmaf(ca, rf, by);                                          \
        ix = __builtin_amdgcn_fmed3f(ix, 1.0f, 258.0f);                       \
        iy = __builtin_amdgcn_fmed3f(iy, 0.0f, 257.0f);                       \
        const float wx = __builtin_amdgcn_fractf(ix);                         \
        const float wy = __builtin_amdgcn_fractf(iy);                         \
        const int x0 = (int)ix;                                               \
        const int y0 = (int)iy;                                               \
        const int wi = y0 * stride + (x0 >> 1) + wbase;                       \
        const unsigned A0 = sw[wi];                                           \
        const unsigned B0 = sw[wi + 1];                                       \
        const unsigned A1 = sw[wi + stride];                                  \
        const unsigned B1 = sw[wi + stride + 1];                              \
        const int sh = (x0 & 1) << 4;                                         \
        const unsigned q0 = __builtin_amdgcn_alignbit(B0, A0, sh);            \
        const unsigned q1 = __builtin_amdgcn_alignbit(B1, A1, sh);            \
        const __half2 h0 = *(const __half2*)&q0;                              \
        const __half2 h1 = *(const __half2*)&q1;                              \
        const __half2 wy2 = __float2half2_rn(wy);                             \
        const __half2 t = __hfma2(wy2, __hsub2(h1, h0), h0);                  \
        const float tl = __low2float(t);                                      \
        const float th = __high2float(t);                                     \
        const float val = fmaf(wx, th - tl, tl);

    float sumA = 0.0f, sumB = 0.0f, sumC = 0.0f;
    {   // segment A: [rs, min(re, r0lo)) -> outer only
        const int e = min(re, r0lo);
        float rf = (float)rs - 127.5f;
        #pragma unroll 4
        for (int r = rs; r < e; ++r, rf += 1.0f) { TAP_BODY sumA += val; }
    }
    {   // segment B: [max(rs, r0lo), min(re, r0hi+1)) -> both
        const int b = max(rs, r0lo);
        const int e = min(re, r0hi + 1);
        float rf = (float)b - 127.5f;
        #pragma unroll 4
        for (int r = b; r < e; ++r, rf += 1.0f) { TAP_BODY sumB += val; }
    }
    {   // segment C: [max(rs, r0hi+1), re) -> outer only
        const int b = max(rs, r0hi + 1);
        float rf = (float)b - 127.5f;
        #pragma unroll 4
        for (int r = b; r < re; ++r, rf += 1.0f) { TAP_BODY sumC += val; }
    }
#undef TAP_BODY

    const float sum0 = sumB;
    const float sum1 = sumA + sumB + sumC;

    // ---- reduce 8 partials; reuse sw as scratch ----
    __syncthreads();
    float* red = (float*)sw;                 // 4 KB of 52.8 KB
    red[(0 * SPLIT + s) * 64 + cl] = sum0;
    red[(1 * SPLIT + s) * 64 + cl] = sum1;
    __syncthreads();

    if (s == 0) {
        float a0 = 0.0f, a1 = 0.0f;
        #pragma unroll
        for (int j = 0; j < SPLIT; ++j) {
            a0 += red[(0 * SPLIT + j) * 64 + cl];
            a1 += red[(1 * SPLIT + j) * 64 + cl];
        }
        // each output location owned by exactly one block -> direct store
        out[(((size_t)n * 2 + 0) * W + c) * NA + a] = a0 * (1.0f / (float)(2 * t0));
        out[(((size_t)n * 2 + 1) * W + c) * NA + a] = a1 * (1.0f / (float)(2 * t1));
    }
}

extern "C" void kernel_launch(void* const* d_in, const int* in_sizes, int n_in,
                              void* d_out, int out_size, void* d_ws, size_t ws_size,
                              hipStream_t stream) {
    const float* x = (const float*)d_in[0];
    const int* index_p = (const int*)d_in[1];
    float* out = (float*)d_out;
    const int N = in_sizes[0] / (W * W); // 4
    dim3 grid(NA, N, 4);                 // 4 column-quarters, full r per block
    radon_kernel<<<grid, 512, 0, stream>>>(x, index_p, out);
}

// Round 23
// 48.153 us; speedup vs baseline: 1.1703x; 1.1703x over previous
//
#include <hip/hip_runtime.h>
#include <hip/hip_fp16.h>

#define W 256
#define NA 180
#define SPLIT 4
#define RWORDS 145            // words per row; odd stride -> axis walks spread over banks
#define ROWBYTES 580
#define ROWS 259              // data rows 1..256 (pixel y + 1); data cols (halfs) 2..257 (pixel x + 2)
#define IMG_WORDS 37555       // ROWS * RWORDS
#define IMG_WORDS_PAD 37568   // padded to 16B multiple (per-image stride in d_ws)
#define NCHUNK 9389           // ceil(IMG_WORDS*4 / 16)

// ---- pre-pass: build the exact LDS layout (fp16 + guards) in d_ws ----
__global__ __launch_bounds__(256) void prep_kernel(
    const float* __restrict__ x, unsigned* __restrict__ ws)
{
    const int row = blockIdx.x;        // 0..258
    const int n = blockIdx.y;
    const int t = threadIdx.x;         // word within row
    if (t >= RWORDS) return;
    unsigned v = 0u;
    if (row >= 1 && row <= 256 && t >= 1 && t <= 128) {
        const int y = row - 1;
        const int px = 2 * (t - 1);    // even -> 8B-aligned float2
        const float2 f2 = *(const float2*)(x + ((size_t)n * W + y) * W + px);
        const __half2 hp = __floats2half2_rn(f2.x, f2.y);
        v = *(const unsigned*)&hp;
    }
    ws[(size_t)n * IMG_WORDS_PAD + row * RWORDS + t] = v;
}

__global__ __launch_bounds__(1024) void radon_kernel(
    const unsigned* __restrict__ ws, const int* __restrict__ index_p,
    float* __restrict__ out)
{
    __shared__ unsigned sw[IMG_WORDS_PAD];   // 150,272 B

    const int a = blockIdx.x;        // angle 0..179
    const int n = blockIdx.y;        // batch
    const int tid = threadIdx.x;
    const int c = tid & (W - 1);     // column 0..255
    const int s = tid >> 8;          // r-chunk 0..3 (wave-uniform)

    // ---- stage prebuilt layout -> LDS via async global_load_lds (no VALU/ds_write) ----
    {
        const char* src = (const char*)(ws + (size_t)n * IMG_WORDS_PAD);
        char* dst = (char*)sw;
        #pragma unroll
        for (int k = 0; k < 10; ++k) {
            const int i = k * 1024 + tid;          // 16B chunk index
            if (i < NCHUNK) {
                __builtin_amdgcn_global_load_lds(
                    (const __attribute__((address_space(1))) void*)(src + (size_t)i * 16),
                    (__attribute__((address_space(3))) void*)(dst + (size_t)i * 16),
                    16, 0, 0);
            }
        }
    }
    __syncthreads();   // compiler drains vmcnt before s_barrier

    const int index = *index_p;
    const int seg[6] = {1, 26, 51, 77, 102, 128};
    const int t0 = seg[4 - index];
    const int t1 = seg[4 - index + 1];

    float sa, ca;
    sincosf((float)a * 0.017453292519943295f, &sa, &ca);

    const float xc = ((2.0f * (float)c + 1.0f) * (1.0f / (float)W)) - 1.0f;
    const float bx = fmaf(128.0f * ca, xc, 129.5f);   // +2 x bias (halfs)
    const float by = fmaf(-128.0f * sa, xc, 128.5f);  // +1 y bias (rows)

    const int r1lo = 128 - t1;
    const int r0lo = 128 - t0, r0hi = 127 + t0;
    const int total = 2 * t1;
    const int chunk = (total + SPLIT - 1) / SPLIT;
    const int rs = r1lo + s * chunk;
    const int re = min(rs + chunk, r1lo + total);

#define TAP_BODY                                                              \
        float ix = fmaf(sa, rf, bx);                                          \
        float iy = fmaf(ca, rf, by);                                          \
        ix = __builtin_amdgcn_fmed3f(ix, 1.0f, 258.0f);                       \
        iy = __builtin_amdgcn_fmed3f(iy, 0.0f, 257.0f);                       \
        const float wx = __builtin_amdgcn_fractf(ix);                         \
        const float wy = __builtin_amdgcn_fractf(iy);                         \
        const int x0 = (int)ix;                                               \
        const int y0 = (int)iy;                                               \
        const int wi = y0 * RWORDS + (x0 >> 1);   /* v_mad_u32_u24 */         \
        const unsigned A0 = sw[wi];                                           \
        const unsigned B0 = sw[wi + 1];                                       \
        const unsigned A1 = sw[wi + RWORDS];                                  \
        const unsigned B1 = sw[wi + RWORDS + 1];                              \
        const int sh = (x0 & 1) << 4;                                         \
        const unsigned q0 = __builtin_amdgcn_alignbit(B0, A0, sh);            \
        const unsigned q1 = __builtin_amdgcn_alignbit(B1, A1, sh);            \
        const __half2 h0 = *(const __half2*)&q0;  /* (v00, v01) row y0 */     \
        const __half2 h1 = *(const __half2*)&q1;  /* (v10, v11) row y0+1 */   \
        const __half2 wy2 = __float2half2_rn(wy);                             \
        const __half2 t = __hfma2(wy2, __hsub2(h1, h0), h0);                  \
        const float tl = __low2float(t);                                      \
        const float th = __high2float(t);                                     \
        const float val = fmaf(wx, th - tl, tl);

    float sumA = 0.0f, sumB = 0.0f, sumC = 0.0f;

    // segment A: [rs, min(re, r0lo)) -> outer only
    {
        const int e = min(re, r0lo);
        float rf = (float)rs - 127.5f;
        #pragma unroll 8
        for (int r = rs; r < e; ++r, rf += 1.0f) { TAP_BODY sumA += val; }
    }
    // segment B: [max(rs, r0lo), min(re, r0hi+1)) -> both masks
    {
        const int b = max(rs, r0lo);
        const int e = min(re, r0hi + 1);
        float rf = (float)b - 127.5f;
        #pragma unroll 8
        for (int r = b; r < e; ++r, rf += 1.0f) { TAP_BODY sumB += val; }
    }
    // segment C: [max(rs, r0hi+1), re) -> outer only
    {
        const int b = max(rs, r0hi + 1);
        float rf = (float)b - 127.5f;
        #pragma unroll 8
        for (int r = b; r < re; ++r, rf += 1.0f) { TAP_BODY sumC += val; }
    }
#undef TAP_BODY

    const float sum0 = sumB;
    const float sum1 = sumA + sumB + sumC;

    // ---- reduce partials; reuse sw as scratch ----
    __syncthreads();
    float* red = (float*)sw;                 // 8 KB of 150 KB
    red[(0 * SPLIT + s) * W + c] = sum0;
    red[(1 * SPLIT + s) * W + c] = sum1;
    __syncthreads();

    if (s == 0) {
        const float acc0 = red[0 * W + c] + red[1 * W + c] + red[2 * W + c] + red[3 * W + c];
        const float* r1p = red + SPLIT * W;
        const float acc1 = r1p[0 * W + c] + r1p[1 * W + c] + r1p[2 * W + c] + r1p[3 * W + c];
        out[(((size_t)n * 2 + 0) * W + c) * NA + a] = acc0 * (1.0f / (float)(2 * t0));
        out[(((size_t)n * 2 + 1) * W + c) * NA + a] = acc1 * (1.0f / (float)(2 * t1));
    }
}

extern "C" void kernel_launch(void* const* d_in, const int* in_sizes, int n_in,
                              void* d_out, int out_size, void* d_ws, size_t ws_size,
                              hipStream_t stream) {
    const float* x = (const float*)d_in[0];
    const int* index_p = (const int*)d_in[1];
    float* out = (float*)d_out;
    const int N = in_sizes[0] / (W * W); // 4
    unsigned* ws = (unsigned*)d_ws;      // N * 150,272 B = 601 KB

    dim3 pgrid(ROWS, N);
    prep_kernel<<<pgrid, 256, 0, stream>>>(x, ws);

    dim3 grid(NA, N);
    radon_kernel<<<grid, 1024, 0, stream>>>(ws, index_p, out);
}

// Round 24
// 47.433 us; speedup vs baseline: 1.1880x; 1.0152x over previous
//
#include <hip/hip_runtime.h>
#include <hip/hip_fp16.h>

#define W 256
#define NA 180
#define SPLIT 4
#define RWORDS 145            // words per row; odd stride -> axis walks spread over banks
#define ROWBYTES 580
#define ROWS 259              // data rows 1..256 (pixel y + 1); data cols (halfs) 2..257 (pixel x + 2)
#define IMG_WORDS 37555       // ROWS * RWORDS
#define IMG_WORDS_PAD 37568   // padded to 16B multiple (per-image stride in d_ws)
#define NCHUNK_W 9392         // chunks written by prep (covers pad)
#define NCHUNK_L 9389         // chunks loaded by main (ceil(IMG_WORDS*4/16))

// ---- pre-pass v2: build the exact LDS layout (fp16 + guards) in d_ws ----
// Fully-active linear chunk mapping: thread -> one 16B chunk (4 words).
__global__ __launch_bounds__(256) void prep_kernel(
    const float* __restrict__ x, unsigned* __restrict__ ws)
{
    const int n = blockIdx.y;
    const int i = blockIdx.x * 256 + threadIdx.x;   // chunk index
    if (i >= NCHUNK_W) return;
    uint4 v = make_uint4(0u, 0u, 0u, 0u);
    unsigned* vp = (unsigned*)&v;
    #pragma unroll
    for (int j = 0; j < 4; ++j) {
        const unsigned w = 4u * i + j;              // word index in padded image
        const unsigned row = w / 145u;              // magic-mul div
        const unsigned t = w - row * 145u;
        if (w < (unsigned)IMG_WORDS &&
            row >= 1u && row <= 256u && t >= 1u && t <= 128u) {
            const int y = (int)row - 1;
            const int px = 2 * ((int)t - 1);        // even -> 8B-aligned float2
            const float2 f2 = *(const float2*)(x + ((size_t)n * W + y) * W + px);
            const __half2 hp = __floats2half2_rn(f2.x, f2.y);
            vp[j] = *(const unsigned*)&hp;
        }
    }
    ((uint4*)(ws + (size_t)n * IMG_WORDS_PAD))[i] = v;
}

__global__ __launch_bounds__(1024) void radon_kernel(
    const unsigned* __restrict__ ws, const int* __restrict__ index_p,
    float* __restrict__ out)
{
    __shared__ unsigned sw[IMG_WORDS_PAD];   // 150,272 B

    const int a = blockIdx.x;        // angle 0..179
    const int n = blockIdx.y;        // batch
    const int tid = threadIdx.x;
    const int c = tid & (W - 1);     // column 0..255
    const int s = tid >> 8;          // r-chunk 0..3 (wave-uniform)

    // ---- issue async staging FIRST (no VALU/ds_write; latency hidden by setup) ----
    {
        const char* src = (const char*)(ws + (size_t)n * IMG_WORDS_PAD);
        char* dst = (char*)sw;
        #pragma unroll
        for (int k = 0; k < 9; ++k) {
            const int i = k * 1024 + tid;
            __builtin_amdgcn_global_load_lds(
                (const __attribute__((address_space(1))) void*)(src + (size_t)i * 16),
                (__attribute__((address_space(3))) void*)(dst + (size_t)i * 16),
                16, 0, 0);
        }
        if (tid < NCHUNK_L - 9 * 1024) {           // 173 tail chunks
            const int i = 9 * 1024 + tid;
            __builtin_amdgcn_global_load_lds(
                (const __attribute__((address_space(1))) void*)(src + (size_t)i * 16),
                (__attribute__((address_space(3))) void*)(dst + (size_t)i * 16),
                16, 0, 0);
        }
    }

    // ---- per-wave setup overlaps the in-flight DMA ----
    const int index = *index_p;
    const int seg[6] = {1, 26, 51, 77, 102, 128};
    const int t0 = seg[4 - index];
    const int t1 = seg[4 - index + 1];

    float sa, ca;
    sincosf((float)a * 0.017453292519943295f, &sa, &ca);

    const float xc = ((2.0f * (float)c + 1.0f) * (1.0f / (float)W)) - 1.0f;
    const float bx = fmaf(128.0f * ca, xc, 129.5f);   // +2 x bias (halfs)
    const float by = fmaf(-128.0f * sa, xc, 128.5f);  // +1 y bias (rows)

    const int r1lo = 128 - t1;
    const int r0lo = 128 - t0, r0hi = 127 + t0;
    const int total = 2 * t1;
    const int chunk = (total + SPLIT - 1) / SPLIT;
    const int rs = r1lo + s * chunk;
    const int re = min(rs + chunk, r1lo + total);

    __syncthreads();   // compiler drains vmcnt before s_barrier

#define TAP_BODY                                                              \
        float ix = fmaf(sa, rf, bx);                                          \
        float iy = fmaf(ca, rf, by);                                          \
        ix = __builtin_amdgcn_fmed3f(ix, 1.0f, 258.0f);                       \
        iy = __builtin_amdgcn_fmed3f(iy, 0.0f, 257.0f);                       \
        const float wx = __builtin_amdgcn_fractf(ix);                         \
        const float wy = __builtin_amdgcn_fractf(iy);                         \
        const int x0 = (int)ix;                                               \
        const int y0 = (int)iy;                                               \
        const int wi = y0 * RWORDS + (x0 >> 1);   /* v_mad_u32_u24 */         \
        const unsigned A0 = sw[wi];                                           \
        const unsigned B0 = sw[wi + 1];                                       \
        const unsigned A1 = sw[wi + RWORDS];                                  \
        const unsigned B1 = sw[wi + RWORDS + 1];                              \
        const int sh = (x0 & 1) << 4;                                         \
        const unsigned q0 = __builtin_amdgcn_alignbit(B0, A0, sh);            \
        const unsigned q1 = __builtin_amdgcn_alignbit(B1, A1, sh);            \
        const __half2 h0 = *(const __half2*)&q0;  /* (v00, v01) row y0 */     \
        const __half2 h1 = *(const __half2*)&q1;  /* (v10, v11) row y0+1 */   \
        const __half2 wy2 = __float2half2_rn(wy);                             \
        const __half2 t = __hfma2(wy2, __hsub2(h1, h0), h0);                  \
        const float tl = __low2float(t);                                      \
        const float th = __high2float(t);                                     \
        const float val = fmaf(wx, th - tl, tl);

    float sumA = 0.0f, sumB = 0.0f, sumC = 0.0f;

    // segment A: [rs, min(re, r0lo)) -> outer only
    {
        const int e = min(re, r0lo);
        float rf = (float)rs - 127.5f;
        #pragma unroll 8
        for (int r = rs; r < e; ++r, rf += 1.0f) { TAP_BODY sumA += val; }
    }
    // segment B: [max(rs, r0lo), min(re, r0hi+1)) -> both masks
    {
        const int b = max(rs, r0lo);
        const int e = min(re, r0hi + 1);
        float rf = (float)b - 127.5f;
        #pragma unroll 8
        for (int r = b; r < e; ++r, rf += 1.0f) { TAP_BODY sumB += val; }
    }
    // segment C: [max(rs, r0hi+1), re) -> outer only
    {
        const int b = max(rs, r0hi + 1);
        float rf = (float)b - 127.5f;
        #pragma unroll 8
        for (int r = b; r < re; ++r, rf += 1.0f) { TAP_BODY sumC += val; }
    }
#undef TAP_BODY

    const float sum0 = sumB;
    const float sum1 = sumA + sumB + sumC;

    // ---- reduce partials; reuse sw as scratch ----
    __syncthreads();
    float* red = (float*)sw;                 // 8 KB of 150 KB
    red[(0 * SPLIT + s) * W + c] = sum0;
    red[(1 * SPLIT + s) * W + c] = sum1;
    __syncthreads();

    if (s == 0) {
        const float acc0 = red[0 * W + c] + red[1 * W + c] + red[2 * W + c] + red[3 * W + c];
        const float* r1p = red + SPLIT * W;
        const float acc1 = r1p[0 * W + c] + r1p[1 * W + c] + r1p[2 * W + c] + r1p[3 * W + c];
        out[(((size_t)n * 2 + 0) * W + c) * NA + a] = acc0 * (1.0f / (float)(2 * t0));
        out[(((size_t)n * 2 + 1) * W + c) * NA + a] = acc1 * (1.0f / (float)(2 * t1));
    }
}

extern "C" void kernel_launch(void* const* d_in, const int* in_sizes, int n_in,
                              void* d_out, int out_size, void* d_ws, size_t ws_size,
                              hipStream_t stream) {
    const float* x = (const float*)d_in[0];
    const int* index_p = (const int*)d_in[1];
    float* out = (float*)d_out;
    const int N = in_sizes[0] / (W * W); // 4
    unsigned* ws = (unsigned*)d_ws;      // N * 150,272 B = 601 KB

    dim3 pgrid((NCHUNK_W + 255) / 256, N);   // 37 x 4 fully-active blocks
    prep_kernel<<<pgrid, 256, 0, stream>>>(x, ws);

    dim3 grid(NA, N);
    radon_kernel<<<grid, 1024, 0, stream>>>(ws, index_p, out);
}